// Round 3
// baseline (5333.143 us; speedup 1.0000x reference)
//
#include <hip/hip_runtime.h>
#include <math.h>

#define N_LINK 100000
#define N_PATH 100000
#define NEDGE  600000
#define D      128
#define HM     256
#define TITERS 4

__device__ __forceinline__ float sigmf(float x) { return 1.0f / (1.0f + __expf(-x)); }
__device__ __forceinline__ float tanhfast(float x) { return 1.0f - 2.0f / (__expf(2.0f * x) + 1.0f); }
__device__ __forceinline__ float b2f(unsigned short u) {
    return __uint_as_float(((unsigned int)u) << 16);
}
__device__ __forceinline__ unsigned short f2b(float f) {
    unsigned int u = __float_as_uint(f);
    unsigned int r = ((u >> 16) & 1u) + 0x7fffu;   // round to nearest even
    return (unsigned short)((u + r) >> 16);
}

__global__ __launch_bounds__(256) void copy_kernel(const float4* __restrict__ src,
                                                   float4* __restrict__ dst, int n4) {
    for (int i = blockIdx.x * 256 + threadIdx.x; i < n4; i += gridDim.x * 256) dst[i] = src[i];
}

__global__ __launch_bounds__(256) void zero_kernel(float4* __restrict__ dst, int n4) {
    float4 z = {0.f, 0.f, 0.f, 0.f};
    for (int i = blockIdx.x * 256 + threadIdx.x; i < n4; i += gridDim.x * 256) dst[i] = z;
}

// Y[n][t] = bias[t] + sum_{i<128} X[n][i] * W[i*HM + t]  -> stored bf16
#define PNB 16
__global__ __launch_bounds__(256) void proj_kernel(const float* __restrict__ X,
                                                   const float* __restrict__ W,
                                                   const float* __restrict__ bias,
                                                   unsigned short* __restrict__ Y, int N) {
    __shared__ float xs[PNB][D];
    int t = threadIdx.x;
    int n0 = blockIdx.x * PNB;
    for (int r = t; r < PNB * D; r += 256) {
        long gi = (long)n0 * D + r;
        xs[r >> 7][r & 127] = (gi < (long)N * D) ? X[gi] : 0.0f;
    }
    __syncthreads();
    float acc[PNB];
    float bv = bias ? bias[t] : 0.0f;
    #pragma unroll
    for (int e = 0; e < PNB; ++e) acc[e] = bv;
    for (int i4 = 0; i4 < D / 4; ++i4) {
        float w0 = W[(i4 * 4 + 0) * HM + t];
        float w1 = W[(i4 * 4 + 1) * HM + t];
        float w2 = W[(i4 * 4 + 2) * HM + t];
        float w3 = W[(i4 * 4 + 3) * HM + t];
        #pragma unroll
        for (int e = 0; e < PNB; ++e) {
            float4 xv = *(const float4*)&xs[e][i4 * 4];
            acc[e] = fmaf(xv.x, w0, acc[e]);
            acc[e] = fmaf(xv.y, w1, acc[e]);
            acc[e] = fmaf(xv.z, w2, acc[e]);
            acc[e] = fmaf(xv.w, w3, acc[e]);
        }
    }
    #pragma unroll
    for (int e = 0; e < PNB; ++e) {
        int n = n0 + e;
        if (n < N) Y[(size_t)n * HM + t] = f2b(acc[e]);
    }
}

// per-edge: h = relu(lp[src] + pp[dst]); msg = h @ W2 + b2; atomicAdd into agg[dst]
#define EB 16
__global__ __launch_bounds__(256) void edge_kernel(const unsigned short* __restrict__ lp,
                                                   const unsigned short* __restrict__ pp,
                                                   const int* __restrict__ src,
                                                   const int* __restrict__ dst,
                                                   const float* __restrict__ W2,
                                                   const float* __restrict__ b2,
                                                   float* __restrict__ agg, int E) {
    __shared__ float hs[EB][HM];
    int t = threadIdx.x;
    int e0 = blockIdx.x * EB;
    int half = t >> 7;          // which edge of a pair
    int c2 = (t & 127) << 1;    // column base (2 cols per thread)
    #pragma unroll
    for (int e = 0; e < EB; e += 2) {
        int ee = e0 + e + half;
        float vx = 0.0f, vy = 0.0f;
        if (ee < E) {
            const unsigned short* lrow = lp + (size_t)src[ee] * HM + c2;
            const unsigned short* prow = pp + (size_t)dst[ee] * HM + c2;
            ushort2 a = *(const ushort2*)lrow;
            ushort2 b = *(const ushort2*)prow;
            vx = b2f(a.x) + b2f(b.x);
            vy = b2f(a.y) + b2f(b.y);
        }
        hs[e + half][c2]     = fmaxf(vx, 0.0f);
        hs[e + half][c2 + 1] = fmaxf(vy, 0.0f);
    }
    __syncthreads();
    int wv = t >> 6, ln = t & 63;
    float acc0[4], acc1[4];
    float ba = b2[ln], bb = b2[ln + 64];
    #pragma unroll
    for (int e = 0; e < 4; ++e) { acc0[e] = ba; acc1[e] = bb; }
    for (int j4 = 0; j4 < HM / 4; ++j4) {
        float4 hv[4];
        #pragma unroll
        for (int e = 0; e < 4; ++e) hv[e] = *(const float4*)&hs[wv * 4 + e][j4 * 4];
        #pragma unroll
        for (int jj = 0; jj < 4; ++jj) {
            int j = j4 * 4 + jj;
            float wa = W2[j * D + ln];
            float wb = W2[j * D + ln + 64];
            #pragma unroll
            for (int e = 0; e < 4; ++e) {
                float h = (jj == 0) ? hv[e].x : (jj == 1) ? hv[e].y : (jj == 2) ? hv[e].z : hv[e].w;
                acc0[e] = fmaf(h, wa, acc0[e]);
                acc1[e] = fmaf(h, wb, acc1[e]);
            }
        }
    }
    #pragma unroll
    for (int e = 0; e < 4; ++e) {
        int ee = e0 + wv * 4 + e;
        if (ee < E) {
            size_t base = (size_t)dst[ee] * D;
            atomicAdd(&agg[base + ln], acc0[e]);
            atomicAdd(&agg[base + ln + 64], acc1[e]);
        }
    }
}

// GRU update; also zeroes agg for the next iteration after reading it.
#define GNB 8
__global__ __launch_bounds__(128) void gru_kernel(float* __restrict__ ps,
                                                  float* __restrict__ agg,
                                                  const float* __restrict__ k,
                                                  const float* __restrict__ rk,
                                                  const float* __restrict__ b, int N) {
    __shared__ float as_[GNB][D];
    __shared__ float hs_[GNB][D];
    int t = threadIdx.x;  // 128 threads, thread t owns gate column t
    int n0 = blockIdx.x * GNB;
    for (int e = 0; e < GNB; ++e) {
        int n = n0 + e;
        if (n < N) {
            as_[e][t] = agg[(size_t)n * D + t];
            hs_[e][t] = ps[(size_t)n * D + t];
            agg[(size_t)n * D + t] = 0.0f;   // re-zero for next iteration
        }
    }
    __syncthreads();
    float az[GNB], ar[GNB], ah[GNB], bz[GNB], br[GNB], bh[GNB];
    float b0 = b[t], b1v = b[D + t], b2v = b[2 * D + t];
    #pragma unroll
    for (int e = 0; e < GNB; ++e) { az[e] = b0; ar[e] = b1v; ah[e] = b2v; bz[e] = br[e] = bh[e] = 0.0f; }
    for (int i4 = 0; i4 < D / 4; ++i4) {
        float kz[4], kr[4], kh[4], rz[4], rr[4], rh[4];
        #pragma unroll
        for (int jj = 0; jj < 4; ++jj) {
            int i = i4 * 4 + jj;
            kz[jj] = k[i * 384 + t];
            kr[jj] = k[i * 384 + D + t];
            kh[jj] = k[i * 384 + 2 * D + t];
            rz[jj] = rk[i * 384 + t];
            rr[jj] = rk[i * 384 + D + t];
            rh[jj] = rk[i * 384 + 2 * D + t];
        }
        #pragma unroll
        for (int e = 0; e < GNB; ++e) {
            float4 av = *(const float4*)&as_[e][i4 * 4];
            float4 hv = *(const float4*)&hs_[e][i4 * 4];
            float aa[4] = {av.x, av.y, av.z, av.w};
            float hh[4] = {hv.x, hv.y, hv.z, hv.w};
            #pragma unroll
            for (int jj = 0; jj < 4; ++jj) {
                az[e] = fmaf(aa[jj], kz[jj], az[e]);
                ar[e] = fmaf(aa[jj], kr[jj], ar[e]);
                ah[e] = fmaf(aa[jj], kh[jj], ah[e]);
                bz[e] = fmaf(hh[jj], rz[jj], bz[e]);
                br[e] = fmaf(hh[jj], rr[jj], br[e]);
                bh[e] = fmaf(hh[jj], rh[jj], bh[e]);
            }
        }
    }
    for (int e = 0; e < GNB; ++e) {
        int n = n0 + e;
        if (n >= N) continue;
        float z = sigmf(az[e] + bz[e]);
        float r = sigmf(ar[e] + br[e]);
        float hcand = tanhfast(ah[e] + r * bh[e]);
        float h = hs_[e][t];
        ps[(size_t)n * D + t] = fmaf(z, h - hcand, hcand);  // z*h + (1-z)*hh
    }
}

// out[n] = relu(ps[n] @ R1 + rb1) @ R2 + rb2
#define RNB 8
__global__ __launch_bounds__(256) void readout_kernel(const float* __restrict__ ps,
                                                      const float* __restrict__ R1,
                                                      const float* __restrict__ rb1,
                                                      const float* __restrict__ R2,
                                                      const float* __restrict__ rb2,
                                                      float* __restrict__ out, int N) {
    __shared__ float xs[RNB][D];
    __shared__ float h1[RNB][HM];
    int t = threadIdx.x;
    int n0 = blockIdx.x * RNB;
    for (int r = t; r < RNB * D; r += 256) {
        long gi = (long)n0 * D + r;
        xs[r >> 7][r & 127] = (gi < (long)N * D) ? ps[gi] : 0.0f;
    }
    __syncthreads();
    float acc[RNB];
    float bv = rb1[t];
    #pragma unroll
    for (int e = 0; e < RNB; ++e) acc[e] = bv;
    for (int i4 = 0; i4 < D / 4; ++i4) {
        float w0 = R1[(i4 * 4 + 0) * HM + t];
        float w1 = R1[(i4 * 4 + 1) * HM + t];
        float w2 = R1[(i4 * 4 + 2) * HM + t];
        float w3 = R1[(i4 * 4 + 3) * HM + t];
        #pragma unroll
        for (int e = 0; e < RNB; ++e) {
            float4 xv = *(const float4*)&xs[e][i4 * 4];
            acc[e] = fmaf(xv.x, w0, acc[e]);
            acc[e] = fmaf(xv.y, w1, acc[e]);
            acc[e] = fmaf(xv.z, w2, acc[e]);
            acc[e] = fmaf(xv.w, w3, acc[e]);
        }
    }
    float r2 = R2[t];
    #pragma unroll
    for (int e = 0; e < RNB; ++e) h1[e][t] = fmaxf(acc[e], 0.0f) * r2;
    __syncthreads();
    int wv = t >> 6, ln = t & 63;
    for (int e = wv; e < RNB; e += 4) {
        float s = h1[e][ln] + h1[e][ln + 64] + h1[e][ln + 128] + h1[e][ln + 192];
        #pragma unroll
        for (int off = 32; off; off >>= 1) s += __shfl_down(s, off, 64);
        if (ln == 0) {
            int n = n0 + e;
            if (n < N) out[n] = s + rb2[0];
        }
    }
}

extern "C" void kernel_launch(void* const* d_in, const int* in_sizes, int n_in,
                              void* d_out, int out_size, void* d_ws, size_t ws_size,
                              hipStream_t stream) {
    const float* link_x = (const float*)d_in[0];
    const float* path_x = (const float*)d_in[1];
    const int*   src    = (const int*)d_in[2];
    const int*   dst    = (const int*)d_in[3];
    const float* W1     = (const float*)d_in[4];
    const float* b1     = (const float*)d_in[5];
    const float* W2     = (const float*)d_in[6];
    const float* b2     = (const float*)d_in[7];
    const float* gk     = (const float*)d_in[8];
    const float* grk    = (const float*)d_in[9];
    const float* gb     = (const float*)d_in[10];
    const float* R1     = (const float*)d_in[11];
    const float* rb1    = (const float*)d_in[12];
    const float* R2     = (const float*)d_in[13];
    const float* rb2    = (const float*)d_in[14];
    float* out = (float*)d_out;

    const size_t psN  = (size_t)N_PATH * D;        // floats
    const size_t lpN  = (size_t)N_LINK * HM;       // bf16 elems
    const size_t ppN  = (size_t)N_PATH * HM;       // bf16 elems
    const size_t needFull = psN * 4 + psN * 4 + lpN * 2 + ppN * 2;

    char* w = (char*)d_ws;
    float* ps;
    bool ps_in_ws = (ws_size >= needFull);
    if (ps_in_ws) { ps = (float*)w; w += psN * 4; }
    else          { ps = (float*)d_in[1]; }        // fallback: mutate input state in place
    float* agg          = (float*)w;  w += psN * 4;
    unsigned short* lp  = (unsigned short*)w; w += lpN * 2;
    unsigned short* pp  = (unsigned short*)w;

    if (ps_in_ws)
        copy_kernel<<<2048, 256, 0, stream>>>((const float4*)path_x, (float4*)ps, (int)(psN / 4));
    zero_kernel<<<2048, 256, 0, stream>>>((float4*)agg, (int)(psN / 4));

    // link-side half of the edge-MLP first layer: link_state is constant -> once
    proj_kernel<<<(N_LINK + PNB - 1) / PNB, 256, 0, stream>>>(link_x, W1, b1, lp, N_LINK);

    for (int it = 0; it < TITERS; ++it) {
        proj_kernel<<<(N_PATH + PNB - 1) / PNB, 256, 0, stream>>>(ps, W1 + D * HM, nullptr, pp, N_PATH);
        edge_kernel<<<(NEDGE + EB - 1) / EB, 256, 0, stream>>>(lp, pp, src, dst, W2, b2, agg, NEDGE);
        gru_kernel<<<(N_PATH + GNB - 1) / GNB, 128, 0, stream>>>(ps, agg, gk, grk, gb, N_PATH);
    }

    readout_kernel<<<(N_PATH + RNB - 1) / RNB, 256, 0, stream>>>(ps, R1, rb1, R2, rb2, out, N_PATH);
}

// Round 6
// 3322.334 us; speedup vs baseline: 1.6052x; 1.6052x over previous
//
#include <hip/hip_runtime.h>
#include <math.h>

#define N_LINK 100000
#define N_PATH 100000
#define NEDGE  600000
#define D      128
#define HM     256
#define TITERS 4

typedef __attribute__((ext_vector_type(8))) short bf16x8;
typedef __attribute__((ext_vector_type(8))) unsigned short u16x8;
typedef __attribute__((ext_vector_type(4))) float f32x4;

__device__ __forceinline__ float sigmf(float x) { return 1.0f / (1.0f + __expf(-x)); }
__device__ __forceinline__ float tanhfast(float x) { return 1.0f - 2.0f / (__expf(2.0f * x) + 1.0f); }
__device__ __forceinline__ float b2f(unsigned short u) {
    return __uint_as_float(((unsigned int)u) << 16);
}
__device__ __forceinline__ unsigned short f2b(float f) {
    unsigned int u = __float_as_uint(f);
    unsigned int r = ((u >> 16) & 1u) + 0x7fffu;   // round to nearest even
    return (unsigned short)((u + r) >> 16);
}

__global__ __launch_bounds__(256) void copy_kernel(const float4* __restrict__ src,
                                                   float4* __restrict__ dst, int n4) {
    for (int i = blockIdx.x * 256 + threadIdx.x; i < n4; i += gridDim.x * 256) dst[i] = src[i];
}

__global__ __launch_bounds__(256) void zero_kernel(float4* __restrict__ dst, int n4) {
    float4 z = {0.f, 0.f, 0.f, 0.f};
    for (int i = blockIdx.x * 256 + threadIdx.x; i < n4; i += gridDim.x * 256) dst[i] = z;
}

// w2bt[c*256 + k] = bf16(W2[k*128 + c])  (transposed, [col][k])
__global__ __launch_bounds__(256) void w2t_kernel(const float* __restrict__ W2,
                                                  unsigned short* __restrict__ w2bt) {
    int idx = blockIdx.x * 256 + threadIdx.x;   // 0..32767
    int k = idx >> 7, c = idx & 127;
    w2bt[c * HM + k] = f2b(W2[(size_t)k * D + c]);
}

// Y[n][t] = bias[t] + sum_{i<128} X[n][i] * W[i*HM + t]  -> stored bf16
#define PNB 16
__global__ __launch_bounds__(256) void proj_kernel(const float* __restrict__ X,
                                                   const float* __restrict__ W,
                                                   const float* __restrict__ bias,
                                                   unsigned short* __restrict__ Y, int N) {
    __shared__ float xs[PNB][D];
    int t = threadIdx.x;
    int n0 = blockIdx.x * PNB;
    for (int r = t; r < PNB * D; r += 256) {
        long gi = (long)n0 * D + r;
        xs[r >> 7][r & 127] = (gi < (long)N * D) ? X[gi] : 0.0f;
    }
    __syncthreads();
    float acc[PNB];
    float bv = bias ? bias[t] : 0.0f;
    #pragma unroll
    for (int e = 0; e < PNB; ++e) acc[e] = bv;
    for (int i4 = 0; i4 < D / 4; ++i4) {
        float w0 = W[(i4 * 4 + 0) * HM + t];
        float w1 = W[(i4 * 4 + 1) * HM + t];
        float w2 = W[(i4 * 4 + 2) * HM + t];
        float w3 = W[(i4 * 4 + 3) * HM + t];
        #pragma unroll
        for (int e = 0; e < PNB; ++e) {
            float4 xv = *(const float4*)&xs[e][i4 * 4];
            acc[e] = fmaf(xv.x, w0, acc[e]);
            acc[e] = fmaf(xv.y, w1, acc[e]);
            acc[e] = fmaf(xv.z, w2, acc[e]);
            acc[e] = fmaf(xv.w, w3, acc[e]);
        }
    }
    #pragma unroll
    for (int e = 0; e < PNB; ++e) {
        int n = n0 + e;
        if (n < N) Y[(size_t)n * HM + t] = f2b(acc[e]);
    }
}

// Per-edge MFMA kernel: 32 edges/block.
// h = relu(lp[src]+pp[dst]) staged bf16 in LDS (XOR-swizzled),
// msg = h @ W2 via mfma_f32_16x16x32_bf16, + b2, atomicAdd into agg[dst].
#define EB 32
__global__ __launch_bounds__(256) void edge_mfma_kernel(const unsigned short* __restrict__ lp,
                                                        const unsigned short* __restrict__ pp,
                                                        const int* __restrict__ src,
                                                        const int* __restrict__ dst,
                                                        const unsigned short* __restrict__ w2bt,
                                                        const float* __restrict__ b2g,
                                                        float* __restrict__ agg) {
    __shared__ char hs[EB * HM * 2];   // 16 KB, swizzled rows of 512B
    __shared__ int sid[EB], did[EB];
    int t = threadIdx.x;
    int e0 = blockIdx.x * EB;
    if (t < EB) { sid[t] = src[e0 + t]; did[t] = dst[e0 + t]; }
    __syncthreads();
    // gather + relu -> bf16 LDS
    #pragma unroll
    for (int i = 0; i < 4; ++i) {
        int r = (t >> 5) + (i << 3);      // 0..31
        int c = (t & 31) << 3;            // 0..248
        u16x8 a = *(const u16x8*)(lp + (size_t)sid[r] * HM + c);
        u16x8 b = *(const u16x8*)(pp + (size_t)did[r] * HM + c);
        u16x8 o;
        #pragma unroll
        for (int j = 0; j < 8; ++j) {
            float v = b2f(a[j]) + b2f(b[j]);
            o[j] = f2b(fmaxf(v, 0.0f));
        }
        int bo = (r << 9) + (c << 1);
        bo ^= (r & 7) << 4;               // bank-conflict swizzle
        *(u16x8*)(hs + bo) = o;
    }
    __syncthreads();
    int wv = t >> 6, l = t & 63;
    int m = wv & 1;                        // M-tile (16 edges)
    int ng = (wv >> 1) * 4;                // first of 4 N-tiles
    f32x4 acc0 = {0.f,0.f,0.f,0.f}, acc1 = acc0, acc2 = acc0, acc3 = acc0;
    int arow = (m << 4) + (l & 15);
    int abase = (arow << 9) + ((l >> 4) << 4);
    int aswz = (arow & 7) << 4;
    const unsigned short* wb = w2bt + (size_t)((ng * 16) + (l & 15)) * HM + ((l >> 4) << 3);
    #pragma unroll
    for (int ks = 0; ks < 8; ++ks) {
        bf16x8 af = *(const bf16x8*)(hs + ((abase + (ks << 6)) ^ aswz));
        bf16x8 b0 = *(const bf16x8*)(wb + (ks << 5));
        bf16x8 b1 = *(const bf16x8*)(wb + 16 * HM + (ks << 5));
        bf16x8 b2v = *(const bf16x8*)(wb + 32 * HM + (ks << 5));
        bf16x8 b3 = *(const bf16x8*)(wb + 48 * HM + (ks << 5));
        acc0 = __builtin_amdgcn_mfma_f32_16x16x32_bf16(af, b0, acc0, 0, 0, 0);
        acc1 = __builtin_amdgcn_mfma_f32_16x16x32_bf16(af, b1, acc1, 0, 0, 0);
        acc2 = __builtin_amdgcn_mfma_f32_16x16x32_bf16(af, b2v, acc2, 0, 0, 0);
        acc3 = __builtin_amdgcn_mfma_f32_16x16x32_bf16(af, b3, acc3, 0, 0, 0);
    }
    // epilogue: C[row=(l>>4)*4+q][col=l&15] per tile (m89-verified layout)
    int rb = (l >> 4) << 2;
    #pragma unroll
    for (int n = 0; n < 4; ++n) {
        int col = (ng + n) * 16 + (l & 15);
        float bb = b2g[col];
        f32x4 acc = (n == 0) ? acc0 : (n == 1) ? acc1 : (n == 2) ? acc2 : acc3;
        #pragma unroll
        for (int q = 0; q < 4; ++q) {
            int e = (m << 4) + rb + q;
            atomicAdd(&agg[(size_t)did[e] * D + col], acc[q] + bb);
        }
    }
}

// GRU update; also zeroes agg for the next iteration after reading it.
#define GNB 16
__global__ __launch_bounds__(128) void gru_kernel(float* __restrict__ ps,
                                                  float* __restrict__ agg,
                                                  const float* __restrict__ k,
                                                  const float* __restrict__ rk,
                                                  const float* __restrict__ b, int N) {
    __shared__ float as_[GNB][D];
    __shared__ float hs_[GNB][D];
    int t = threadIdx.x;  // 128 threads, thread t owns gate column t
    int n0 = blockIdx.x * GNB;
    for (int e = 0; e < GNB; ++e) {
        int n = n0 + e;
        if (n < N) {
            as_[e][t] = agg[(size_t)n * D + t];
            hs_[e][t] = ps[(size_t)n * D + t];
            agg[(size_t)n * D + t] = 0.0f;   // re-zero for next iteration
        }
    }
    __syncthreads();
    float az[GNB], ar[GNB], ah[GNB], bz[GNB], br[GNB], bh[GNB];
    float b0 = b[t], b1v = b[D + t], b2v = b[2 * D + t];
    #pragma unroll
    for (int e = 0; e < GNB; ++e) { az[e] = b0; ar[e] = b1v; ah[e] = b2v; bz[e] = br[e] = bh[e] = 0.0f; }
    for (int i4 = 0; i4 < D / 4; ++i4) {
        float kz[4], kr[4], kh[4], rz[4], rr[4], rh[4];
        #pragma unroll
        for (int jj = 0; jj < 4; ++jj) {
            int i = i4 * 4 + jj;
            kz[jj] = k[i * 384 + t];
            kr[jj] = k[i * 384 + D + t];
            kh[jj] = k[i * 384 + 2 * D + t];
            rz[jj] = rk[i * 384 + t];
            rr[jj] = rk[i * 384 + D + t];
            rh[jj] = rk[i * 384 + 2 * D + t];
        }
        #pragma unroll
        for (int e = 0; e < GNB; ++e) {
            float4 av = *(const float4*)&as_[e][i4 * 4];
            float4 hv = *(const float4*)&hs_[e][i4 * 4];
            float aa[4] = {av.x, av.y, av.z, av.w};
            float hh[4] = {hv.x, hv.y, hv.z, hv.w};
            #pragma unroll
            for (int jj = 0; jj < 4; ++jj) {
                az[e] = fmaf(aa[jj], kz[jj], az[e]);
                ar[e] = fmaf(aa[jj], kr[jj], ar[e]);
                ah[e] = fmaf(aa[jj], kh[jj], ah[e]);
                bz[e] = fmaf(hh[jj], rz[jj], bz[e]);
                br[e] = fmaf(hh[jj], rr[jj], br[e]);
                bh[e] = fmaf(hh[jj], rh[jj], bh[e]);
            }
        }
    }
    for (int e = 0; e < GNB; ++e) {
        int n = n0 + e;
        if (n >= N) continue;
        float z = sigmf(az[e] + bz[e]);
        float r = sigmf(ar[e] + br[e]);
        float hcand = tanhfast(ah[e] + r * bh[e]);
        float h = hs_[e][t];
        ps[(size_t)n * D + t] = fmaf(z, h - hcand, hcand);  // z*h + (1-z)*hh
    }
}

// out[n] = relu(ps[n] @ R1 + rb1) @ R2 + rb2
#define RNB 8
__global__ __launch_bounds__(256) void readout_kernel(const float* __restrict__ ps,
                                                      const float* __restrict__ R1,
                                                      const float* __restrict__ rb1,
                                                      const float* __restrict__ R2,
                                                      const float* __restrict__ rb2,
                                                      float* __restrict__ out, int N) {
    __shared__ float xs[RNB][D];
    __shared__ float h1[RNB][HM];
    int t = threadIdx.x;
    int n0 = blockIdx.x * RNB;
    for (int r = t; r < RNB * D; r += 256) {
        long gi = (long)n0 * D + r;
        xs[r >> 7][r & 127] = (gi < (long)N * D) ? ps[gi] : 0.0f;
    }
    __syncthreads();
    float acc[RNB];
    float bv = rb1[t];
    #pragma unroll
    for (int e = 0; e < RNB; ++e) acc[e] = bv;
    for (int i4 = 0; i4 < D / 4; ++i4) {
        float w0 = R1[(i4 * 4 + 0) * HM + t];
        float w1 = R1[(i4 * 4 + 1) * HM + t];
        float w2 = R1[(i4 * 4 + 2) * HM + t];
        float w3 = R1[(i4 * 4 + 3) * HM + t];
        #pragma unroll
        for (int e = 0; e < RNB; ++e) {
            float4 xv = *(const float4*)&xs[e][i4 * 4];
            acc[e] = fmaf(xv.x, w0, acc[e]);
            acc[e] = fmaf(xv.y, w1, acc[e]);
            acc[e] = fmaf(xv.z, w2, acc[e]);
            acc[e] = fmaf(xv.w, w3, acc[e]);
        }
    }
    float r2 = R2[t];
    #pragma unroll
    for (int e = 0; e < RNB; ++e) h1[e][t] = fmaxf(acc[e], 0.0f) * r2;
    __syncthreads();
    int wv = t >> 6, ln = t & 63;
    for (int e = wv; e < RNB; e += 4) {
        float s = h1[e][ln] + h1[e][ln + 64] + h1[e][ln + 128] + h1[e][ln + 192];
        #pragma unroll
        for (int off = 32; off; off >>= 1) s += __shfl_down(s, off, 64);
        if (ln == 0) {
            int n = n0 + e;
            if (n < N) out[n] = s + rb2[0];
        }
    }
}

extern "C" void kernel_launch(void* const* d_in, const int* in_sizes, int n_in,
                              void* d_out, int out_size, void* d_ws, size_t ws_size,
                              hipStream_t stream) {
    const float* link_x = (const float*)d_in[0];
    const float* path_x = (const float*)d_in[1];
    const int*   src    = (const int*)d_in[2];
    const int*   dst    = (const int*)d_in[3];
    const float* W1     = (const float*)d_in[4];
    const float* b1     = (const float*)d_in[5];
    const float* W2     = (const float*)d_in[6];
    const float* b2     = (const float*)d_in[7];
    const float* gk     = (const float*)d_in[8];
    const float* grk    = (const float*)d_in[9];
    const float* gb     = (const float*)d_in[10];
    const float* R1     = (const float*)d_in[11];
    const float* rb1    = (const float*)d_in[12];
    const float* R2     = (const float*)d_in[13];
    const float* rb2    = (const float*)d_in[14];
    float* out = (float*)d_out;

    const size_t psN  = (size_t)N_PATH * D;        // floats
    const size_t lpN  = (size_t)N_LINK * HM;       // bf16 elems
    const size_t ppN  = (size_t)N_PATH * HM;       // bf16 elems
    const size_t w2tN = (size_t)D * HM;            // bf16 elems (64KB)
    const size_t needFull = psN * 4 + psN * 4 + lpN * 2 + ppN * 2 + w2tN * 2;

    char* w = (char*)d_ws;
    float* ps;
    bool ps_in_ws = (ws_size >= needFull);
    if (ps_in_ws) { ps = (float*)w; w += psN * 4; }
    else          { ps = (float*)d_in[1]; }        // fallback: mutate input state in place
    float* agg           = (float*)w;  w += psN * 4;
    unsigned short* lp   = (unsigned short*)w; w += lpN * 2;
    unsigned short* pp   = (unsigned short*)w; w += ppN * 2;
    unsigned short* w2bt = (unsigned short*)w;

    if (ps_in_ws)
        copy_kernel<<<2048, 256, 0, stream>>>((const float4*)path_x, (float4*)ps, (int)(psN / 4));
    zero_kernel<<<2048, 256, 0, stream>>>((float4*)agg, (int)(psN / 4));
    w2t_kernel<<<(D * HM) / 256, 256, 0, stream>>>(W2, w2bt);

    // link-side half of the edge-MLP first layer: link_state is constant -> once
    proj_kernel<<<(N_LINK + PNB - 1) / PNB, 256, 0, stream>>>(link_x, W1, b1, lp, N_LINK);

    for (int it = 0; it < TITERS; ++it) {
        proj_kernel<<<(N_PATH + PNB - 1) / PNB, 256, 0, stream>>>(ps, W1 + D * HM, nullptr, pp, N_PATH);
        edge_mfma_kernel<<<NEDGE / EB, 256, 0, stream>>>(lp, pp, src, dst, w2bt, b2, agg);
        gru_kernel<<<(N_PATH + GNB - 1) / GNB, 128, 0, stream>>>(ps, agg, gk, grk, gb, N_PATH);
    }

    readout_kernel<<<(N_PATH + RNB - 1) / RNB, 256, 0, stream>>>(ps, R1, rb1, R2, rb2, out, N_PATH);
}

// Round 9
// 2542.671 us; speedup vs baseline: 2.0975x; 1.3066x over previous
//
#include <hip/hip_runtime.h>
#include <math.h>

#define N_LINK 100000
#define N_PATH 100000
#define NEDGE  600000
#define D      128
#define HM     256
#define TITERS 4

typedef __attribute__((ext_vector_type(8))) short bf16x8;
typedef __attribute__((ext_vector_type(8))) unsigned short u16x8;
typedef __attribute__((ext_vector_type(4))) float f32x4;

__device__ __forceinline__ float sigmf(float x) { return 1.0f / (1.0f + __expf(-x)); }
__device__ __forceinline__ float tanhfast(float x) { return 1.0f - 2.0f / (__expf(2.0f * x) + 1.0f); }
__device__ __forceinline__ float b2f(unsigned short u) {
    return __uint_as_float(((unsigned int)u) << 16);
}
__device__ __forceinline__ unsigned short f2b(float f) {
    unsigned int u = __float_as_uint(f);
    unsigned int r = ((u >> 16) & 1u) + 0x7fffu;   // round to nearest even
    return (unsigned short)((u + r) >> 16);
}
__device__ __forceinline__ u16x8 pack8(float4 a, float4 b) {
    u16x8 o;
    o[0]=f2b(a.x); o[1]=f2b(a.y); o[2]=f2b(a.z); o[3]=f2b(a.w);
    o[4]=f2b(b.x); o[5]=f2b(b.y); o[6]=f2b(b.z); o[7]=f2b(b.w);
    return o;
}

__global__ __launch_bounds__(256) void copy_kernel(const float4* __restrict__ src,
                                                   float4* __restrict__ dst, int n4) {
    for (int i = blockIdx.x * 256 + threadIdx.x; i < n4; i += gridDim.x * 256) dst[i] = src[i];
}

__global__ __launch_bounds__(256) void zero_kernel(float4* __restrict__ dst, int n4) {
    float4 z = {0.f, 0.f, 0.f, 0.f};
    for (int i = blockIdx.x * 256 + threadIdx.x; i < n4; i += gridDim.x * 256) dst[i] = z;
}

// w2bt[c*256 + k] = bf16(W2[k*128 + c])  (transposed, [col][k])
__global__ __launch_bounds__(256) void w2t_kernel(const float* __restrict__ W2,
                                                  unsigned short* __restrict__ w2bt) {
    int idx = blockIdx.x * 256 + threadIdx.x;   // 0..32767
    int k = idx >> 7, c = idx & 127;
    w2bt[c * HM + k] = f2b(W2[(size_t)k * D + c]);
}

// w1lt[c*128+k] = bf16(W1[k*256+c]); w1pt[c*128+k] = bf16(W1[(k+128)*256+c])
__global__ __launch_bounds__(256) void w1t_kernel(const float* __restrict__ W1,
                                                  unsigned short* __restrict__ w1lt,
                                                  unsigned short* __restrict__ w1pt) {
    int idx = blockIdx.x * 256 + threadIdx.x;   // 0..32767 (256 cols x 128 k)
    int c = idx >> 7, k = idx & 127;
    w1lt[idx] = f2b(W1[(size_t)k * HM + c]);
    w1pt[idx] = f2b(W1[(size_t)(k + D) * HM + c]);
}

// KT[c*128+k] = bf16(K[k*384+c])  (gru kernels, [col][k], 384 cols)
__global__ __launch_bounds__(256) void gkt_kernel(const float* __restrict__ K,
                                                  unsigned short* __restrict__ KT) {
    int idx = blockIdx.x * 256 + threadIdx.x;   // 0..49151
    int c = idx >> 7, k = idx & 127;
    KT[idx] = f2b(K[(size_t)k * 384 + c]);
}

// MFMA projection: Y[n][c] = bf16( bias[c] + sum_k X[n][k]*W[c][k] ), 32 rows/block
#define PMB 32
__global__ __launch_bounds__(256) void proj_mfma_kernel(const float* __restrict__ X,
                                                        const unsigned short* __restrict__ wbt,
                                                        const float* __restrict__ bias,
                                                        unsigned short* __restrict__ Y) {
    __shared__ char xs[PMB * D * 2];   // 8 KB bf16 swizzled (256B rows)
    int t = threadIdx.x;
    int n0 = blockIdx.x * PMB;
    #pragma unroll
    for (int i = 0; i < 2; ++i) {
        int r = (t >> 4) + (i << 4);
        int c = (t & 15) << 3;
        size_t gi = (size_t)(n0 + r) * D + c;
        float4 a = *(const float4*)(X + gi);
        float4 b = *(const float4*)(X + gi + 4);
        int bo = (r << 8) + (c << 1);
        bo ^= (r & 7) << 4;
        *(u16x8*)(xs + bo) = pack8(a, b);
    }
    __syncthreads();
    int wv = t >> 6, l = t & 63;
    int m = wv & 1;
    int nt0 = (wv >> 1) << 3;              // 0 or 8 (N-tile base; 16 tiles of 16 cols)
    f32x4 acc[8];
    #pragma unroll
    for (int i = 0; i < 8; ++i) acc[i] = (f32x4){0.f, 0.f, 0.f, 0.f};
    int ar = (m << 4) + (l & 15);
    int abase = (ar << 8) + ((l >> 4) << 4);
    int aswz = (ar & 7) << 4;
    const unsigned short* wb = wbt + (size_t)((nt0 << 4) + (l & 15)) * D + ((l >> 4) << 3);
    #pragma unroll
    for (int ks = 0; ks < 4; ++ks) {
        bf16x8 af = *(const bf16x8*)(xs + ((abase + (ks << 6)) ^ aswz));
        #pragma unroll
        for (int nt = 0; nt < 8; ++nt) {
            bf16x8 bf = *(const bf16x8*)(wb + (size_t)(nt << 4) * D + (ks << 5));
            acc[nt] = __builtin_amdgcn_mfma_f32_16x16x32_bf16(af, bf, acc[nt], 0, 0, 0);
        }
    }
    int rb = (l >> 4) << 2;
    #pragma unroll
    for (int nt = 0; nt < 8; ++nt) {
        int col = ((nt0 + nt) << 4) + (l & 15);
        float bv = bias ? bias[col] : 0.0f;
        #pragma unroll
        for (int q = 0; q < 4; ++q) {
            int row = (m << 4) + rb + q;
            Y[(size_t)(n0 + row) * HM + col] = f2b(acc[nt][q] + bv);
        }
    }
}

// Per-edge MFMA kernel: 32 edges/block (validated round 6).
#define EB 32
__global__ __launch_bounds__(256) void edge_mfma_kernel(const unsigned short* __restrict__ lp,
                                                        const unsigned short* __restrict__ pp,
                                                        const int* __restrict__ src,
                                                        const int* __restrict__ dst,
                                                        const unsigned short* __restrict__ w2bt,
                                                        const float* __restrict__ b2g,
                                                        float* __restrict__ agg) {
    __shared__ char hs[EB * HM * 2];   // 16 KB, swizzled rows of 512B
    __shared__ int sid[EB], did[EB];
    int t = threadIdx.x;
    int e0 = blockIdx.x * EB;
    if (t < EB) { sid[t] = src[e0 + t]; did[t] = dst[e0 + t]; }
    __syncthreads();
    #pragma unroll
    for (int i = 0; i < 4; ++i) {
        int r = (t >> 5) + (i << 3);
        int c = (t & 31) << 3;
        u16x8 a = *(const u16x8*)(lp + (size_t)sid[r] * HM + c);
        u16x8 b = *(const u16x8*)(pp + (size_t)did[r] * HM + c);
        u16x8 o;
        #pragma unroll
        for (int j = 0; j < 8; ++j) {
            float v = b2f(a[j]) + b2f(b[j]);
            o[j] = f2b(fmaxf(v, 0.0f));
        }
        int bo = (r << 9) + (c << 1);
        bo ^= (r & 7) << 4;
        *(u16x8*)(hs + bo) = o;
    }
    __syncthreads();
    int wv = t >> 6, l = t & 63;
    int m = wv & 1;
    int ng = (wv >> 1) * 4;
    f32x4 acc0 = {0.f,0.f,0.f,0.f}, acc1 = acc0, acc2 = acc0, acc3 = acc0;
    int arow = (m << 4) + (l & 15);
    int abase = (arow << 9) + ((l >> 4) << 4);
    int aswz = (arow & 7) << 4;
    const unsigned short* wb = w2bt + (size_t)((ng * 16) + (l & 15)) * HM + ((l >> 4) << 3);
    #pragma unroll
    for (int ks = 0; ks < 8; ++ks) {
        bf16x8 af = *(const bf16x8*)(hs + ((abase + (ks << 6)) ^ aswz));
        bf16x8 b0 = *(const bf16x8*)(wb + (ks << 5));
        bf16x8 b1 = *(const bf16x8*)(wb + 16 * HM + (ks << 5));
        bf16x8 b2v = *(const bf16x8*)(wb + 32 * HM + (ks << 5));
        bf16x8 b3 = *(const bf16x8*)(wb + 48 * HM + (ks << 5));
        acc0 = __builtin_amdgcn_mfma_f32_16x16x32_bf16(af, b0, acc0, 0, 0, 0);
        acc1 = __builtin_amdgcn_mfma_f32_16x16x32_bf16(af, b1, acc1, 0, 0, 0);
        acc2 = __builtin_amdgcn_mfma_f32_16x16x32_bf16(af, b2v, acc2, 0, 0, 0);
        acc3 = __builtin_amdgcn_mfma_f32_16x16x32_bf16(af, b3, acc3, 0, 0, 0);
    }
    int rb = (l >> 4) << 2;
    #pragma unroll
    for (int n = 0; n < 4; ++n) {
        int col = (ng + n) * 16 + (l & 15);
        float bb = b2g[col];
        f32x4 acc = (n == 0) ? acc0 : (n == 1) ? acc1 : (n == 2) ? acc2 : acc3;
        #pragma unroll
        for (int q = 0; q < 4; ++q) {
            int e = (m << 4) + rb + q;
            atomicAdd(&agg[(size_t)did[e] * D + col], acc[q] + bb);
        }
    }
}

// MFMA GRU: 32 nodes/block. z/r gates accumulate agg@k AND ps@rk in one acc;
// h-gate keeps two accs (needs r * gh_h). Old state h kept fp32 in LDS.
// Re-zeroes agg during staging.
#define GMB 32
__global__ __launch_bounds__(256) void gru_mfma_kernel(float* __restrict__ ps,
                                                       float* __restrict__ agg,
                                                       const unsigned short* __restrict__ gkt,
                                                       const unsigned short* __restrict__ grkt,
                                                       const float* __restrict__ gb) {
    __shared__ char as_[GMB * D * 2];   // agg bf16, 8 KB swizzled
    __shared__ char hs_[GMB * D * 2];   // ps  bf16, 8 KB swizzled
    __shared__ float hf_[GMB][D];       // ps  fp32, 16 KB
    int t = threadIdx.x;
    int n0 = blockIdx.x * GMB;
    #pragma unroll
    for (int i = 0; i < 2; ++i) {
        int r = (t >> 4) + (i << 4);
        int c = (t & 15) << 3;
        size_t gi = (size_t)(n0 + r) * D + c;
        float4 a0 = *(const float4*)(agg + gi);
        float4 a1 = *(const float4*)(agg + gi + 4);
        float4 p0 = *(const float4*)(ps + gi);
        float4 p1 = *(const float4*)(ps + gi + 4);
        float4 z4 = {0.f, 0.f, 0.f, 0.f};
        *(float4*)(agg + gi) = z4;          // re-zero for next iteration
        *(float4*)(agg + gi + 4) = z4;
        int bo = (r << 8) + (c << 1);
        bo ^= (r & 7) << 4;
        *(u16x8*)(as_ + bo) = pack8(a0, a1);
        *(u16x8*)(hs_ + bo) = pack8(p0, p1);
        *(float4*)(&hf_[r][c]) = p0;
        *(float4*)(&hf_[r][c + 4]) = p1;
    }
    __syncthreads();
    int wv = t >> 6, l = t & 63;
    int m = wv & 1;
    int cb = (wv >> 1) << 6;               // column base: 0 or 64 (of 128 gate cols)
    f32x4 az[4], arr[4], ah1[4], ah2[4];
    #pragma unroll
    for (int i = 0; i < 4; ++i) {
        az[i] = (f32x4){0.f,0.f,0.f,0.f}; arr[i] = az[i]; ah1[i] = az[i]; ah2[i] = az[i];
    }
    int ar = (m << 4) + (l & 15);
    int abase = (ar << 8) + ((l >> 4) << 4);
    int aswz = (ar & 7) << 4;
    int klane = (l >> 4) << 3;
    #pragma unroll
    for (int ks = 0; ks < 4; ++ks) {
        bf16x8 af = *(const bf16x8*)(as_ + ((abase + (ks << 6)) ^ aswz));
        bf16x8 pf = *(const bf16x8*)(hs_ + ((abase + (ks << 6)) ^ aswz));
        int ko = klane + (ks << 5);
        #pragma unroll
        for (int ct = 0; ct < 4; ++ct) {
            int colz = cb + (ct << 4) + (l & 15);
            bf16x8 kz = *(const bf16x8*)(gkt  + (size_t)colz * D + ko);
            bf16x8 rz = *(const bf16x8*)(grkt + (size_t)colz * D + ko);
            az[ct] = __builtin_amdgcn_mfma_f32_16x16x32_bf16(af, kz, az[ct], 0, 0, 0);
            az[ct] = __builtin_amdgcn_mfma_f32_16x16x32_bf16(pf, rz, az[ct], 0, 0, 0);
            bf16x8 kr = *(const bf16x8*)(gkt  + (size_t)(128 + colz) * D + ko);
            bf16x8 rr = *(const bf16x8*)(grkt + (size_t)(128 + colz) * D + ko);
            arr[ct] = __builtin_amdgcn_mfma_f32_16x16x32_bf16(af, kr, arr[ct], 0, 0, 0);
            arr[ct] = __builtin_amdgcn_mfma_f32_16x16x32_bf16(pf, rr, arr[ct], 0, 0, 0);
            bf16x8 kh = *(const bf16x8*)(gkt  + (size_t)(256 + colz) * D + ko);
            bf16x8 rh = *(const bf16x8*)(grkt + (size_t)(256 + colz) * D + ko);
            ah1[ct] = __builtin_amdgcn_mfma_f32_16x16x32_bf16(af, kh, ah1[ct], 0, 0, 0);
            ah2[ct] = __builtin_amdgcn_mfma_f32_16x16x32_bf16(pf, rh, ah2[ct], 0, 0, 0);
        }
    }
    int rb = (l >> 4) << 2;
    #pragma unroll
    for (int ct = 0; ct < 4; ++ct) {
        int c = cb + (ct << 4) + (l & 15);
        float bz = gb[c], br = gb[128 + c], bh = gb[256 + c];
        #pragma unroll
        for (int q = 0; q < 4; ++q) {
            int row = (m << 4) + rb + q;
            float z = sigmf(az[ct][q] + bz);
            float r = sigmf(arr[ct][q] + br);
            float hh = tanhfast(ah1[ct][q] + bh + r * ah2[ct][q]);
            float h = hf_[row][c];
            ps[(size_t)(n0 + row) * D + c] = fmaf(z, h - hh, hh);  // z*h + (1-z)*hh
        }
    }
}

// out[n] = relu(ps[n] @ R1 + rb1) @ R2 + rb2
#define RNB 8
__global__ __launch_bounds__(256) void readout_kernel(const float* __restrict__ ps,
                                                      const float* __restrict__ R1,
                                                      const float* __restrict__ rb1,
                                                      const float* __restrict__ R2,
                                                      const float* __restrict__ rb2,
                                                      float* __restrict__ out, int N) {
    __shared__ float xs[RNB][D];
    __shared__ float h1[RNB][HM];
    int t = threadIdx.x;
    int n0 = blockIdx.x * RNB;
    for (int r = t; r < RNB * D; r += 256) {
        long gi = (long)n0 * D + r;
        xs[r >> 7][r & 127] = (gi < (long)N * D) ? ps[gi] : 0.0f;
    }
    __syncthreads();
    float acc[RNB];
    float bv = rb1[t];
    #pragma unroll
    for (int e = 0; e < RNB; ++e) acc[e] = bv;
    for (int i4 = 0; i4 < D / 4; ++i4) {
        float w0 = R1[(i4 * 4 + 0) * HM + t];
        float w1 = R1[(i4 * 4 + 1) * HM + t];
        float w2 = R1[(i4 * 4 + 2) * HM + t];
        float w3 = R1[(i4 * 4 + 3) * HM + t];
        #pragma unroll
        for (int e = 0; e < RNB; ++e) {
            float4 xv = *(const float4*)&xs[e][i4 * 4];
            acc[e] = fmaf(xv.x, w0, acc[e]);
            acc[e] = fmaf(xv.y, w1, acc[e]);
            acc[e] = fmaf(xv.z, w2, acc[e]);
            acc[e] = fmaf(xv.w, w3, acc[e]);
        }
    }
    float r2 = R2[t];
    #pragma unroll
    for (int e = 0; e < RNB; ++e) h1[e][t] = fmaxf(acc[e], 0.0f) * r2;
    __syncthreads();
    int wv = t >> 6, ln = t & 63;
    for (int e = wv; e < RNB; e += 4) {
        float s = h1[e][ln] + h1[e][ln + 64] + h1[e][ln + 128] + h1[e][ln + 192];
        #pragma unroll
        for (int off = 32; off; off >>= 1) s += __shfl_down(s, off, 64);
        if (ln == 0) {
            int n = n0 + e;
            if (n < N) out[n] = s + rb2[0];
        }
    }
}

extern "C" void kernel_launch(void* const* d_in, const int* in_sizes, int n_in,
                              void* d_out, int out_size, void* d_ws, size_t ws_size,
                              hipStream_t stream) {
    const float* link_x = (const float*)d_in[0];
    const float* path_x = (const float*)d_in[1];
    const int*   src    = (const int*)d_in[2];
    const int*   dst    = (const int*)d_in[3];
    const float* W1     = (const float*)d_in[4];
    const float* b1     = (const float*)d_in[5];
    const float* W2     = (const float*)d_in[6];
    const float* b2     = (const float*)d_in[7];
    const float* gk     = (const float*)d_in[8];
    const float* grk    = (const float*)d_in[9];
    const float* gb     = (const float*)d_in[10];
    const float* R1     = (const float*)d_in[11];
    const float* rb1    = (const float*)d_in[12];
    const float* R2     = (const float*)d_in[13];
    const float* rb2    = (const float*)d_in[14];
    float* out = (float*)d_out;

    const size_t psN  = (size_t)N_PATH * D;        // floats
    const size_t lpN  = (size_t)N_LINK * HM;       // bf16 elems
    const size_t ppN  = (size_t)N_PATH * HM;       // bf16 elems
    const size_t w2tN = (size_t)D * HM;            // 32768 bf16
    const size_t w1tN = (size_t)HM * D;            // 32768 bf16 each half
    const size_t gktN = (size_t)384 * D;           // 49152 bf16 each
    const size_t needFull = psN * 4 + psN * 4 + lpN * 2 + ppN * 2 +
                            (w2tN + 2 * w1tN + 2 * gktN) * 2;

    char* w = (char*)d_ws;
    float* ps;
    bool ps_in_ws = (ws_size >= needFull);
    if (ps_in_ws) { ps = (float*)w; w += psN * 4; }
    else          { ps = (float*)d_in[1]; }        // fallback: mutate input state in place
    float* agg           = (float*)w;  w += psN * 4;
    unsigned short* lp   = (unsigned short*)w; w += lpN * 2;
    unsigned short* pp   = (unsigned short*)w; w += ppN * 2;
    unsigned short* w2bt = (unsigned short*)w; w += w2tN * 2;
    unsigned short* w1lt = (unsigned short*)w; w += w1tN * 2;
    unsigned short* w1pt = (unsigned short*)w; w += w1tN * 2;
    unsigned short* gktb = (unsigned short*)w; w += gktN * 2;
    unsigned short* grkt = (unsigned short*)w;

    if (ps_in_ws)
        copy_kernel<<<2048, 256, 0, stream>>>((const float4*)path_x, (float4*)ps, (int)(psN / 4));
    zero_kernel<<<2048, 256, 0, stream>>>((float4*)agg, (int)(psN / 4));
    w2t_kernel<<<(D * HM) / 256, 256, 0, stream>>>(W2, w2bt);
    w1t_kernel<<<(HM * D) / 256, 256, 0, stream>>>(W1, w1lt, w1pt);
    gkt_kernel<<<(384 * D) / 256, 256, 0, stream>>>(gk, gktb);
    gkt_kernel<<<(384 * D) / 256, 256, 0, stream>>>(grk, grkt);

    // link-side half of the edge-MLP first layer: link_state is constant -> once
    proj_mfma_kernel<<<N_LINK / PMB, 256, 0, stream>>>(link_x, w1lt, b1, lp);

    for (int it = 0; it < TITERS; ++it) {
        proj_mfma_kernel<<<N_PATH / PMB, 256, 0, stream>>>(ps, w1pt, nullptr, pp);
        edge_mfma_kernel<<<NEDGE / EB, 256, 0, stream>>>(lp, pp, src, dst, w2bt, b2, agg);
        gru_mfma_kernel<<<N_PATH / GMB, 256, 0, stream>>>(ps, agg, gktb, grkt, gb);
    }

    readout_kernel<<<(N_PATH + RNB - 1) / RNB, 256, 0, stream>>>(ps, R1, rb1, R2, rb2, out, N_PATH);
}